// Round 1
// baseline (128.146 us; speedup 1.0000x reference)
//
#include <hip/hip_runtime.h>

#define TLEN 4096
#define NSHIFT 21
#define SHIFT 10
#define PAD 16
#define NTHR 256

// One block per row. Computes argmax-Pearson shift + masked MSE for the row.
__global__ __launch_bounds__(NTHR, 4)
void shift_corr_kernel(const float* __restrict__ x, const float* __restrict__ y,
                       float* __restrict__ mse_out)
{
    __shared__ __align__(16) float lx[TLEN];
    __shared__ __align__(16) float ly[TLEN + 2 * PAD];   // zero-padded both sides
    __shared__ float red[4][NSHIFT + 4];
    __shared__ float edge[8][SHIFT + 1];
    __shared__ int   sh_s;
    __shared__ float sh_n;

    const int tid = threadIdx.x;
    const int row = blockIdx.x;
    const int lane = tid & 63;
    const int wid  = tid >> 6;

    const float4* xg = (const float4*)(x + (size_t)row * TLEN);
    const float4* yg = (const float4*)(y + (size_t)row * TLEN);
    float4* lx4  = (float4*)lx;
    float4* lyi4 = (float4*)(ly + PAD);   // interior (PAD=16 floats -> 64B aligned)
    const float4* ly4 = (const float4*)ly;

    // ---- stage rows into LDS (coalesced float4) ----
    #pragma unroll
    for (int it = 0; it < 4; ++it) {
        int c = tid + it * NTHR;
        lx4[c]  = xg[c];
        lyi4[c] = yg[c];
    }
    if (tid < PAD) { ly[tid] = 0.f; ly[PAD + TLEN + tid] = 0.f; }
    __syncthreads();

    // ---- main pass: 21-lag cross-corr + full-row sums ----
    float sxy[NSHIFT];
    #pragma unroll
    for (int k = 0; k < NSHIFT; ++k) sxy[k] = 0.f;
    float sx = 0.f, sxx = 0.f, sy = 0.f, syy = 0.f;

    #pragma unroll 1
    for (int it = 0; it < 4; ++it) {
        int c = tid + it * NTHR;            // chunk of 4 elems, i0 = 4c
        float4 xv4 = lx4[c];
        float xv[4] = {xv4.x, xv4.y, xv4.z, xv4.w};
        // y window covers [i0-12, i0+16) = 28 floats, aligned float4 reads
        float yw[28];
        #pragma unroll
        for (int k = 0; k < 7; ++k) {
            float4 v = ly4[c + 1 + k];
            yw[4*k+0] = v.x; yw[4*k+1] = v.y; yw[4*k+2] = v.z; yw[4*k+3] = v.w;
        }
        #pragma unroll
        for (int l = 0; l < 4; ++l) {
            float xl = xv[l];
            sx += xl; sxx = fmaf(xl, xl, sxx);
            float yl = yw[12 + l];
            sy += yl; syy = fmaf(yl, yl, syy);
            // y[i+s] is at window offset l + s + 12 = l + si + 2
            #pragma unroll
            for (int si = 0; si < NSHIFT; ++si)
                sxy[si] = fmaf(xl, yw[l + si + 2], sxy[si]);
        }
    }

    // ---- block reduction of 25 partials ----
    float vals[NSHIFT + 4];
    #pragma unroll
    for (int k = 0; k < NSHIFT; ++k) vals[k] = sxy[k];
    vals[21] = sx; vals[22] = sxx; vals[23] = sy; vals[24] = syy;

    #pragma unroll
    for (int k = 0; k < NSHIFT + 4; ++k) {
        float v = vals[k];
        #pragma unroll
        for (int off = 32; off > 0; off >>= 1)
            v += __shfl_down(v, off, 64);
        if (lane == 0) red[wid][k] = v;
    }
    __syncthreads();

    // ---- thread 0: edge sums, Pearson per shift, argmax (first-max) ----
    if (tid == 0) {
        float ax=0,axx=0,ay=0,ayy=0,bx=0,bxx=0,by=0,byy=0;
        #pragma unroll
        for (int k = 0; k <= SHIFT; ++k) {
            edge[0][k]=ax; edge[1][k]=axx; edge[2][k]=ay; edge[3][k]=ayy;
            edge[4][k]=bx; edge[5][k]=bxx; edge[6][k]=by; edge[7][k]=byy;
            float xf = lx[k],          xl2 = lx[TLEN-1-k];
            float yf = ly[PAD + k],    yl2 = ly[PAD + TLEN-1-k];
            ax += xf;  axx = fmaf(xf, xf, axx);
            bx += xl2; bxx = fmaf(xl2, xl2, bxx);
            ay += yf;  ayy = fmaf(yf, yf, ayy);
            by += yl2; byy = fmaf(yl2, yl2, byy);
        }
        float Sx  = red[0][21]+red[1][21]+red[2][21]+red[3][21];
        float Sxx = red[0][22]+red[1][22]+red[2][22]+red[3][22];
        float Sy  = red[0][23]+red[1][23]+red[2][23]+red[3][23];
        float Syy = red[0][24]+red[1][24]+red[2][24]+red[3][24];

        float best = -1e30f; int sbest = 0;
        for (int si = 0; si < NSHIFT; ++si) {
            int s = si - SHIFT;
            int k = s >= 0 ? s : -s;
            float n = (float)(TLEN - k);
            // s>=0: x-window drops top k, y-window drops bottom k; s<0 reversed
            float Sxs  = Sx  - (s >= 0 ? edge[4][k] : edge[0][k]);
            float Sxxs = Sxx - (s >= 0 ? edge[5][k] : edge[1][k]);
            float Sys  = Sy  - (s >= 0 ? edge[2][k] : edge[6][k]);
            float Syys = Syy - (s >= 0 ? edge[3][k] : edge[7][k]);
            float Sxys = red[0][si]+red[1][si]+red[2][si]+red[3][si];
            float cov = Sxys - Sxs * Sys / n;
            float vx  = Sxxs - Sxs * Sxs / n;
            float vy  = Syys - Sys * Sys / n;
            float corr = cov * rsqrtf(vx * vy);
            if (corr > best) { best = corr; sbest = s; }
        }
        sh_s = sbest;
        sh_n = (float)(TLEN - (sbest >= 0 ? sbest : -sbest));
    }
    __syncthreads();

    // ---- phase 2: masked MSE at best shift (exact same form as reference) ----
    const int s = sh_s;
    float acc = 0.f;
    #pragma unroll 1
    for (int it = 0; it < 4; ++it) {
        int c = tid + it * NTHR;
        #pragma unroll
        for (int l = 0; l < 4; ++l) {
            int i = 4 * c + l;
            float d = lx[i] - ly[PAD + i + s];
            acc = ((unsigned)(i + s) < (unsigned)TLEN) ? fmaf(d, d, acc) : acc;
        }
    }
    #pragma unroll
    for (int off = 32; off > 0; off >>= 1)
        acc += __shfl_down(acc, off, 64);
    if (lane == 0) red[wid][0] = acc;
    __syncthreads();
    if (tid == 0) {
        float tot = red[0][0] + red[1][0] + red[2][0] + red[3][0];
        mse_out[row] = tot / sh_n;
    }
}

// Deterministic final mean over B rows.
__global__ __launch_bounds__(NTHR)
void finalize_kernel(const float* __restrict__ mse, float* __restrict__ out, int B)
{
    __shared__ float red[4];
    int tid = threadIdx.x;
    int lane = tid & 63, wid = tid >> 6;
    float a = 0.f;
    for (int i = tid; i < B; i += NTHR) a += mse[i];
    #pragma unroll
    for (int off = 32; off > 0; off >>= 1)
        a += __shfl_down(a, off, 64);
    if (lane == 0) red[wid] = a;
    __syncthreads();
    if (tid == 0) out[0] = (red[0] + red[1] + red[2] + red[3]) / (float)B;
}

extern "C" void kernel_launch(void* const* d_in, const int* in_sizes, int n_in,
                              void* d_out, int out_size, void* d_ws, size_t ws_size,
                              hipStream_t stream)
{
    const float* x = (const float*)d_in[0];
    const float* y = (const float*)d_in[1];
    float* out = (float*)d_out;
    float* ws  = (float*)d_ws;
    const int B = in_sizes[0] / TLEN;

    shift_corr_kernel<<<B, NTHR, 0, stream>>>(x, y, ws);
    finalize_kernel<<<1, NTHR, 0, stream>>>(ws, out, B);
}

// Round 4
// 103.149 us; speedup vs baseline: 1.2423x; 1.2423x over previous
//
#include <hip/hip_runtime.h>

#define TLEN 4096
#define NQ (TLEN / 4)
#define NSHIFT 21
#define SHIFT 10
#define PADF 16   // zero-pad floats each side of y row (4 quads)
#define NTHR 256

// One block (256 thr) per row. One streaming pass computes 21-lag cross-corr
// + moment sums; butterfly reduce-scatter; lanes 0..20 of wave 0 do per-shift
// Pearson + MSE-by-formula; argmax shuffle; lane 0 writes per-row MSE.
__global__ __launch_bounds__(NTHR, 8)
void shift_corr_kernel(const float* __restrict__ x, const float* __restrict__ y,
                       float* __restrict__ mse_out)
{
    __shared__ __align__(16) float ly[TLEN + 2 * PADF];
    __shared__ float redbuf[4][32];

    const int tid  = threadIdx.x;
    const int row  = blockIdx.x;
    const int lane = tid & 63;
    const int wid  = tid >> 6;

    const float* xrow = x + (size_t)row * TLEN;
    const float4* xg = (const float4*)xrow;
    const float4* yg = (const float4*)(y + (size_t)row * TLEN);
    float4* lyi4 = (float4*)(ly + PADF);
    const float4* ly4 = (const float4*)ly;

    // ---- stage y row into LDS (zero-padded), x stays in global ----
    #pragma unroll
    for (int it = 0; it < 4; ++it) {
        int c = tid + it * NTHR;
        lyi4[c] = yg[c];
    }
    if (tid < PADF) { ly[tid] = 0.f; ly[PADF + TLEN + tid] = 0.f; }
    __syncthreads();

    // ---- main pass: 21-lag cross-corr + full-row moment sums ----
    float sxy[NSHIFT];
    #pragma unroll
    for (int k = 0; k < NSHIFT; ++k) sxy[k] = 0.f;
    float sx = 0.f, sxx = 0.f, sy = 0.f, syy = 0.f;

    #pragma unroll 1
    for (int it = 0; it < 4; ++it) {
        int c = tid + it * NTHR;          // quad index; elems i0 = 4c
        float4 xv4 = xg[c];               // global, coalesced
        float xv[4] = {xv4.x, xv4.y, xv4.z, xv4.w};
        // y window [4c-12, 4c+15]: 7 aligned LDS quads, lane-consecutive
        float yw[28];
        #pragma unroll
        for (int k = 0; k < 7; ++k) {
            float4 v = ly4[c + 1 + k];
            yw[4*k+0] = v.x; yw[4*k+1] = v.y; yw[4*k+2] = v.z; yw[4*k+3] = v.w;
        }
        #pragma unroll
        for (int l = 0; l < 4; ++l) {
            float xl = xv[l];
            sx += xl; sxx = fmaf(xl, xl, sxx);
            float yl = yw[12 + l];
            sy += yl; syy = fmaf(yl, yl, syy);
            #pragma unroll
            for (int si = 0; si < NSHIFT; ++si)
                sxy[si] = fmaf(xl, yw[l + si + 2], sxy[si]);
        }
    }

    // ---- per-wave butterfly reduce-scatter: 32 shuffles total ----
    // After rounds on lane-bits 5..1, lane l holds value index (l>>1)&31.
    float vals[32];
    #pragma unroll
    for (int k = 0; k < NSHIFT; ++k) vals[k] = sxy[k];
    vals[21] = sx; vals[22] = sxx; vals[23] = sy; vals[24] = syy;
    #pragma unroll
    for (int k = NSHIFT + 4; k < 32; ++k) vals[k] = 0.f;

    #pragma unroll
    for (int b = 5; b >= 1; --b) {
        const int mask = 1 << b;
        const int half = 1 << (b - 1);
        const bool keepLow = ((lane >> b) & 1) == 0;
        #pragma unroll
        for (int j = 0; j < half; ++j) {
            float send = keepLow ? vals[j + half] : vals[j];
            float recv = __shfl_xor(send, mask, 64);
            vals[j] = (keepLow ? vals[j] : vals[j + half]) + recv;
        }
    }
    {   // lanes l and l^1 hold same value; final add gives full wave sum
        float recv = __shfl_xor(vals[0], 1, 64);
        float tot = vals[0] + recv;
        if ((lane & 1) == 0) redbuf[wid][(lane >> 1) & 31] = tot;
    }
    __syncthreads();

    // ---- wave 0: cross-wave sum + per-shift Pearson, wave-parallel ----
    if (wid == 0) {
        const int v = lane & 31;
        float S = redbuf[0][v] + redbuf[1][v] + redbuf[2][v] + redbuf[3][v];
        float Sx  = __shfl(S, 21, 64);
        float Sxx = __shfl(S, 22, 64);
        float Sy  = __shfl(S, 23, 64);
        float Syy = __shfl(S, 24, 64);

        float corr = -1e30f, mse = 0.f;
        int bsi = lane;
        if (lane < NSHIFT) {
            const int s = lane - SHIFT;
            const int k = s < 0 ? -s : s;
            float ax = 0.f, axx = 0.f, ay = 0.f, ayy = 0.f;
            if (s >= 0) {
                // drop last k of x, first k of y
                for (int j = 0; j < k; ++j) {
                    float xv = xrow[TLEN - 1 - j];
                    float yv = ly[PADF + j];
                    ax += xv; axx = fmaf(xv, xv, axx);
                    ay += yv; ayy = fmaf(yv, yv, ayy);
                }
            } else {
                // drop first k of x, last k of y
                for (int j = 0; j < k; ++j) {
                    float xv = xrow[j];
                    float yv = ly[PADF + TLEN - 1 - j];
                    ax += xv; axx = fmaf(xv, xv, axx);
                    ay += yv; ayy = fmaf(yv, yv, ayy);
                }
            }
            const float n = (float)(TLEN - k);
            float Sxs = Sx - ax, Sxxs = Sxx - axx;
            float Sys = Sy - ay, Syys = Syy - ayy;
            float Sxys = S;                 // lane si holds sxy[si]
            float cov = Sxys - Sxs * Sys / n;
            float vx  = Sxxs - Sxs * Sxs / n;
            float vy  = Syys - Sys * Sys / n;
            corr = cov * rsqrtf(vx * vy);
            mse  = (Sxxs + Syys - 2.f * Sxys) / n;
        }
        // argmax over lanes, first-max tie-break (smallest shift index)
        #pragma unroll
        for (int m = 32; m >= 1; m >>= 1) {
            float oc = __shfl_xor(corr, m, 64);
            float om = __shfl_xor(mse,  m, 64);
            int  osi = __shfl_xor(bsi,  m, 64);
            if (oc > corr || (oc == corr && osi < bsi)) {
                corr = oc; mse = om; bsi = osi;
            }
        }
        if (lane == 0) mse_out[row] = mse;
    }
}

// Deterministic final mean over B rows.
__global__ __launch_bounds__(NTHR)
void finalize_kernel(const float* __restrict__ mse, float* __restrict__ out, int B)
{
    __shared__ float red[4];
    int tid = threadIdx.x;
    int lane = tid & 63, wid = tid >> 6;
    float a = 0.f;
    for (int i = tid; i < B; i += NTHR) a += mse[i];
    #pragma unroll
    for (int off = 32; off > 0; off >>= 1)
        a += __shfl_down(a, off, 64);
    if (lane == 0) red[wid] = a;
    __syncthreads();
    if (tid == 0) out[0] = (red[0] + red[1] + red[2] + red[3]) / (float)B;
}

extern "C" void kernel_launch(void* const* d_in, const int* in_sizes, int n_in,
                              void* d_out, int out_size, void* d_ws, size_t ws_size,
                              hipStream_t stream)
{
    const float* x = (const float*)d_in[0];
    const float* y = (const float*)d_in[1];
    float* out = (float*)d_out;
    float* ws  = (float*)d_ws;
    const int B = in_sizes[0] / TLEN;

    shift_corr_kernel<<<B, NTHR, 0, stream>>>(x, y, ws);
    finalize_kernel<<<1, NTHR, 0, stream>>>(ws, out, B);
}

// Round 5
// 100.460 us; speedup vs baseline: 1.2756x; 1.0268x over previous
//
#include <hip/hip_runtime.h>

#define TLEN 4096
#define NQ (TLEN / 4)
#define NSHIFT 21
#define SHIFT 10
#define PADF 16   // zero-pad floats each side of y row (4 quads)
#define NTHR 256

// One block (256 thr) per row. One streaming pass computes 21-lag cross-corr
// + moment sums; butterfly reduce-scatter; lanes 0..20 of wave 0 do per-shift
// Pearson + MSE-by-formula; argmax shuffle; lane 0 writes per-row MSE.
// launch_bounds(256,6): cap ~85 VGPR — (256,8)'s 64-VGPR cap risks inner-loop
// spills/serialization; 6 blocks/CU is plenty (LDS allows 9).
__global__ __launch_bounds__(NTHR, 6)
void shift_corr_kernel(const float* __restrict__ x, const float* __restrict__ y,
                       float* __restrict__ mse_out)
{
    __shared__ __align__(16) float ly[TLEN + 2 * PADF];
    __shared__ float redbuf[4][32];

    const int tid  = threadIdx.x;
    const int row  = blockIdx.x;
    const int lane = tid & 63;
    const int wid  = tid >> 6;

    const float* xrow = x + (size_t)row * TLEN;
    const float4* xg = (const float4*)xrow;
    const float4* yg = (const float4*)(y + (size_t)row * TLEN);
    float4* lyi4 = (float4*)(ly + PADF);
    const float4* ly4 = (const float4*)ly;

    // ---- stage y row into LDS (zero-padded); preload x quads to registers ----
    #pragma unroll
    for (int it = 0; it < 4; ++it) {
        int c = tid + it * NTHR;
        lyi4[c] = yg[c];
    }
    float4 xq[4];
    #pragma unroll
    for (int it = 0; it < 4; ++it)
        xq[it] = xg[tid + it * NTHR];   // in flight during staging + barrier
    if (tid < PADF) { ly[tid] = 0.f; ly[PADF + TLEN + tid] = 0.f; }
    __syncthreads();

    // ---- main pass: 21-lag cross-corr + full-row moment sums ----
    float sxy[NSHIFT];
    #pragma unroll
    for (int k = 0; k < NSHIFT; ++k) sxy[k] = 0.f;
    float sx = 0.f, sxx = 0.f, sy = 0.f, syy = 0.f;

    #pragma unroll
    for (int it = 0; it < 4; ++it) {
        int c = tid + it * NTHR;          // quad index; elems i0 = 4c
        float xv[4] = {xq[it].x, xq[it].y, xq[it].z, xq[it].w};
        // y window [4c-12, 4c+15]: 7 aligned LDS quads, lane-consecutive
        float yw[28];
        #pragma unroll
        for (int k = 0; k < 7; ++k) {
            float4 v = ly4[c + 1 + k];
            yw[4*k+0] = v.x; yw[4*k+1] = v.y; yw[4*k+2] = v.z; yw[4*k+3] = v.w;
        }
        #pragma unroll
        for (int l = 0; l < 4; ++l) {
            float xl = xv[l];
            sx += xl; sxx = fmaf(xl, xl, sxx);
            float yl = yw[12 + l];
            sy += yl; syy = fmaf(yl, yl, syy);
            #pragma unroll
            for (int si = 0; si < NSHIFT; ++si)
                sxy[si] = fmaf(xl, yw[l + si + 2], sxy[si]);
        }
    }

    // ---- per-wave butterfly reduce-scatter: 33 shuffles total ----
    // After rounds on lane-bits 5..1, lane l holds value index (l>>1)&31.
    float vals[32];
    #pragma unroll
    for (int k = 0; k < NSHIFT; ++k) vals[k] = sxy[k];
    vals[21] = sx; vals[22] = sxx; vals[23] = sy; vals[24] = syy;
    #pragma unroll
    for (int k = NSHIFT + 4; k < 32; ++k) vals[k] = 0.f;

    #pragma unroll
    for (int b = 5; b >= 1; --b) {
        const int mask = 1 << b;
        const int half = 1 << (b - 1);
        const bool keepLow = ((lane >> b) & 1) == 0;
        #pragma unroll
        for (int j = 0; j < half; ++j) {
            float send = keepLow ? vals[j + half] : vals[j];
            float recv = __shfl_xor(send, mask, 64);
            vals[j] = (keepLow ? vals[j] : vals[j + half]) + recv;
        }
    }
    {   // lanes l and l^1 hold same value; final add gives full wave sum
        float recv = __shfl_xor(vals[0], 1, 64);
        float tot = vals[0] + recv;
        if ((lane & 1) == 0) redbuf[wid][(lane >> 1) & 31] = tot;
    }
    __syncthreads();

    // ---- wave 0: cross-wave sum + per-shift Pearson, wave-parallel ----
    if (wid == 0) {
        const int v = lane & 31;
        float S = redbuf[0][v] + redbuf[1][v] + redbuf[2][v] + redbuf[3][v];
        float Sx  = __shfl(S, 21, 64);
        float Sxx = __shfl(S, 22, 64);
        float Sy  = __shfl(S, 23, 64);
        float Syy = __shfl(S, 24, 64);

        float corr = -1e30f, mse = 0.f;
        int bsi = lane;
        if (lane < NSHIFT) {
            const int s = lane - SHIFT;
            const int k = s < 0 ? -s : s;
            float ax = 0.f, axx = 0.f, ay = 0.f, ayy = 0.f;
            if (s >= 0) {
                // drop last k of x, first k of y
                for (int j = 0; j < k; ++j) {
                    float xv = xrow[TLEN - 1 - j];
                    float yv = ly[PADF + j];
                    ax += xv; axx = fmaf(xv, xv, axx);
                    ay += yv; ayy = fmaf(yv, yv, ayy);
                }
            } else {
                // drop first k of x, last k of y
                for (int j = 0; j < k; ++j) {
                    float xv = xrow[j];
                    float yv = ly[PADF + TLEN - 1 - j];
                    ax += xv; axx = fmaf(xv, xv, axx);
                    ay += yv; ayy = fmaf(yv, yv, ayy);
                }
            }
            const float n = (float)(TLEN - k);
            float Sxs = Sx - ax, Sxxs = Sxx - axx;
            float Sys = Sy - ay, Syys = Syy - ayy;
            float Sxys = S;                 // lane si holds sxy[si]
            float cov = Sxys - Sxs * Sys / n;
            float vx  = Sxxs - Sxs * Sxs / n;
            float vy  = Syys - Sys * Sys / n;
            corr = cov * rsqrtf(vx * vy);
            mse  = (Sxxs + Syys - 2.f * Sxys) / n;
        }
        // argmax over lanes, first-max tie-break (smallest shift index)
        #pragma unroll
        for (int m = 32; m >= 1; m >>= 1) {
            float oc = __shfl_xor(corr, m, 64);
            float om = __shfl_xor(mse,  m, 64);
            int  osi = __shfl_xor(bsi,  m, 64);
            if (oc > corr || (oc == corr && osi < bsi)) {
                corr = oc; mse = om; bsi = osi;
            }
        }
        if (lane == 0) mse_out[row] = mse;
    }
}

// Deterministic final mean over B rows.
__global__ __launch_bounds__(NTHR)
void finalize_kernel(const float* __restrict__ mse, float* __restrict__ out, int B)
{
    __shared__ float red[4];
    int tid = threadIdx.x;
    int lane = tid & 63, wid = tid >> 6;
    float a = 0.f;
    for (int i = tid; i < B; i += NTHR) a += mse[i];
    #pragma unroll
    for (int off = 32; off > 0; off >>= 1)
        a += __shfl_down(a, off, 64);
    if (lane == 0) red[wid] = a;
    __syncthreads();
    if (tid == 0) out[0] = (red[0] + red[1] + red[2] + red[3]) / (float)B;
}

extern "C" void kernel_launch(void* const* d_in, const int* in_sizes, int n_in,
                              void* d_out, int out_size, void* d_ws, size_t ws_size,
                              hipStream_t stream)
{
    const float* x = (const float*)d_in[0];
    const float* y = (const float*)d_in[1];
    float* out = (float*)d_out;
    float* ws  = (float*)d_ws;
    const int B = in_sizes[0] / TLEN;

    shift_corr_kernel<<<B, NTHR, 0, stream>>>(x, y, ws);
    finalize_kernel<<<1, NTHR, 0, stream>>>(ws, out, B);
}